// Round 1
// baseline (130.240 us; speedup 1.0000x reference)
//
#include <hip/hip_runtime.h>
#include <stdint.h>
#include <limits.h>

// MarginLoss: loss = mean(max(logits - logits[argmax(labels)] + 1.0, 1e-6))
// Two streaming passes (argmax over labels, clamped sum over logits) —
// memory-bound, floor = 2 * 256 MiB / 6.3 TB/s ~= 85 us.

static constexpr int BLOCK = 256;
static constexpr int GRID  = 2048;   // ~8 blocks/CU on 256 CUs, grid-stride

#define MARGIN_F 1.0f
#define EPS_F    1e-6f

// Pack (value, index) so that unsigned-max picks larger value, tie -> smaller
// index (jnp.argmax first-occurrence semantics). Signed value mapped to
// offset-binary in the high 32 bits; ~index in the low 32 bits.
__device__ __forceinline__ unsigned long long pack_key(int v, unsigned idx) {
    return ((unsigned long long)((unsigned)v ^ 0x80000000u) << 32)
         | (unsigned long long)(~idx);
}

__global__ __launch_bounds__(BLOCK) void argmax_labels_kernel(
        const int* __restrict__ labels, int n,
        unsigned long long* __restrict__ key_out) {
    int      bv = INT_MIN;
    unsigned bi = 0xFFFFFFFFu;

    const int n4 = n >> 2;
    const int4* __restrict__ l4 = (const int4*)labels;
    const int stride = gridDim.x * blockDim.x;
    for (int i = blockIdx.x * blockDim.x + threadIdx.x; i < n4; i += stride) {
        int4 v = l4[i];
        unsigned b = ((unsigned)i) << 2;
        // increasing index order + strict '>' keeps the first occurrence
        if (v.x > bv) { bv = v.x; bi = b;     }
        if (v.y > bv) { bv = v.y; bi = b + 1; }
        if (v.z > bv) { bv = v.z; bi = b + 2; }
        if (v.w > bv) { bv = v.w; bi = b + 3; }
    }
    // scalar tail (indices beyond the vectorized region are larger, so
    // strict '>' still preserves first-occurrence semantics)
    if (blockIdx.x == 0) {
        for (int i = (n4 << 2) + (int)threadIdx.x; i < n; i += (int)blockDim.x) {
            int v = labels[i];
            if (v > bv) { bv = v; bi = (unsigned)i; }
        }
    }

    unsigned long long best = pack_key(bv, bi);
    // 64-lane wave reduction (wavefront = 64 on CDNA)
    #pragma unroll
    for (int off = 32; off > 0; off >>= 1) {
        unsigned long long o = __shfl_down(best, off, 64);
        if (o > best) best = o;
    }
    __shared__ unsigned long long sm[BLOCK / 64];
    const int lane = threadIdx.x & 63;
    const int wv   = threadIdx.x >> 6;
    if (lane == 0) sm[wv] = best;
    __syncthreads();
    if (threadIdx.x == 0) {
        unsigned long long b = sm[0];
        #pragma unroll
        for (int w = 1; w < BLOCK / 64; ++w)
            if (sm[w] > b) b = sm[w];
        atomicMax(key_out, b);
    }
}

__global__ __launch_bounds__(BLOCK) void clamped_sum_kernel(
        const float* __restrict__ logits, int n,
        const unsigned long long* __restrict__ key_in,
        double* __restrict__ acc) {
    // broadcast max_score to the block (one dependent load, negligible)
    __shared__ float s_score;
    if (threadIdx.x == 0) {
        unsigned idx = ~(unsigned)(*key_in);
        s_score = logits[idx];
    }
    __syncthreads();
    const float c = MARGIN_F - s_score;   // x - s + margin == x + c

    const int n4 = n >> 2;
    const float4* __restrict__ l4 = (const float4*)logits;
    const int stride = gridDim.x * blockDim.x;
    float partial = 0.0f;   // ~128 values of O(1) magnitude per thread: fp32 fine
    for (int i = blockIdx.x * blockDim.x + threadIdx.x; i < n4; i += stride) {
        float4 v = l4[i];
        partial += fmaxf(v.x + c, EPS_F) + fmaxf(v.y + c, EPS_F)
                 + fmaxf(v.z + c, EPS_F) + fmaxf(v.w + c, EPS_F);
    }
    if (blockIdx.x == 0) {
        for (int i = (n4 << 2) + (int)threadIdx.x; i < n; i += (int)blockDim.x)
            partial += fmaxf(logits[i] + c, EPS_F);
    }

    // 64-lane wave reduction, then cross-wave via LDS
    #pragma unroll
    for (int off = 32; off > 0; off >>= 1)
        partial += __shfl_down(partial, off, 64);
    __shared__ float sm[BLOCK / 64];
    const int lane = threadIdx.x & 63;
    const int wv   = threadIdx.x >> 6;
    if (lane == 0) sm[wv] = partial;
    __syncthreads();
    if (threadIdx.x == 0) {
        float bsum = sm[0];
        #pragma unroll
        for (int w = 1; w < BLOCK / 64; ++w) bsum += sm[w];
        atomicAdd(acc, (double)bsum);   // 2048 adds into a double: tiny error
    }
}

__global__ void finalize_kernel(const double* __restrict__ acc,
                                float* __restrict__ out, int n) {
    out[0] = (float)(*acc / (double)n);
}

extern "C" void kernel_launch(void* const* d_in, const int* in_sizes, int n_in,
                              void* d_out, int out_size, void* d_ws, size_t ws_size,
                              hipStream_t stream) {
    const float* logits = (const float*)d_in[0];
    const int*   labels = (const int*)d_in[1];
    const int n_logits = in_sizes[0];
    const int n_labels = in_sizes[1];

    unsigned long long* key = (unsigned long long*)d_ws;
    double*             acc = (double*)((char*)d_ws + 8);

    // ws is NOT re-poisoned between replays -> clear our 16 bytes every call
    hipMemsetAsync(d_ws, 0, 16, stream);

    argmax_labels_kernel<<<GRID, BLOCK, 0, stream>>>(labels, n_labels, key);
    clamped_sum_kernel<<<GRID, BLOCK, 0, stream>>>(logits, n_logits, key, acc);
    finalize_kernel<<<1, 1, 0, stream>>>(acc, (float*)d_out, n_logits);
}

// Round 2
// 106.827 us; speedup vs baseline: 1.2192x; 1.2192x over previous
//
#include <hip/hip_runtime.h>
#include <stdint.h>

// MarginLoss: loss = mean(max(logits - logits[argmax(labels)] + margin, eps))
// labels are one-hot (single 1), so argmax == position of the unique nonzero.
// Two mandatory streaming passes: 256 MiB labels + 256 MiB logits = 512 MiB
// read @ ~6.3 TB/s achievable -> ~85 us floor. Memory-bound.

static constexpr int BLOCK = 256;
static constexpr int GRID  = 2048;   // 8 blocks/CU on 256 CUs, fully resident

#define MARGIN_F 1.0f
#define EPS_F    1e-6f

// ws layout: [0 .. GRID) float block partials, then int found-index at +8192.
// Every slot is unconditionally written each call except idx (written by the
// unique thread that sees the one-hot 1) -> no zero-init / memset needed.

__global__ __launch_bounds__(BLOCK) void find_label_kernel(
        const int* __restrict__ labels, int n,
        int* __restrict__ idx_out) {
    const int n4     = n >> 2;
    const int stride = GRID * BLOCK;
    const int tid    = blockIdx.x * BLOCK + threadIdx.x;
    const int4* __restrict__ l4 = (const int4*)labels;

    int i = tid;
    for (; i + 3 * stride < n4; i += 4 * stride) {
        int4 a = l4[i];
        int4 b = l4[i + stride];
        int4 c = l4[i + 2 * stride];
        int4 d = l4[i + 3 * stride];
        int oa = a.x | a.y | a.z | a.w;
        int ob = b.x | b.y | b.z | b.w;
        int oc = c.x | c.y | c.z | c.w;
        int od = d.x | d.y | d.z | d.w;
        if (oa | ob | oc | od) {            // taken by at most one int4 group
            int4 vs[4] = {a, b, c, d};
            int  bs[4] = {i, i + stride, i + 2 * stride, i + 3 * stride};
            for (int k = 0; k < 4; ++k) {
                int4 v = vs[k];
                if (v.x | v.y | v.z | v.w) {
                    int base = bs[k] << 2;
                    if (v.x) *idx_out = base;
                    else if (v.y) *idx_out = base + 1;
                    else if (v.z) *idx_out = base + 2;
                    else          *idx_out = base + 3;
                }
            }
        }
    }
    for (; i < n4; i += stride) {
        int4 v = l4[i];
        if (v.x | v.y | v.z | v.w) {
            int base = i << 2;
            if (v.x) *idx_out = base;
            else if (v.y) *idx_out = base + 1;
            else if (v.z) *idx_out = base + 2;
            else          *idx_out = base + 3;
        }
    }
    // scalar tail (n not multiple of 4) — absent for n = 2^26 but kept generic
    if (blockIdx.x == 0) {
        for (int j = (n4 << 2) + (int)threadIdx.x; j < n; j += BLOCK)
            if (labels[j]) *idx_out = j;
    }
}

__global__ __launch_bounds__(BLOCK) void clamped_sum_kernel(
        const float* __restrict__ logits, int n,
        const int* __restrict__ idx_in,
        float* __restrict__ partials) {
    __shared__ float s_score;
    if (threadIdx.x == 0) s_score = logits[*idx_in];
    __syncthreads();
    const float c = MARGIN_F - s_score;       // x - s + margin == x + c

    const int n4     = n >> 2;
    const int stride = GRID * BLOCK;
    const int tid    = blockIdx.x * BLOCK + threadIdx.x;
    const float4* __restrict__ l4 = (const float4*)logits;

    float p0 = 0.f, p1 = 0.f, p2 = 0.f, p3 = 0.f;
    int i = tid;
    for (; i + 3 * stride < n4; i += 4 * stride) {
        float4 a = l4[i];
        float4 b = l4[i + stride];
        float4 cc = l4[i + 2 * stride];
        float4 d = l4[i + 3 * stride];
        p0 += fmaxf(a.x + c, EPS_F) + fmaxf(a.y + c, EPS_F)
            + fmaxf(a.z + c, EPS_F) + fmaxf(a.w + c, EPS_F);
        p1 += fmaxf(b.x + c, EPS_F) + fmaxf(b.y + c, EPS_F)
            + fmaxf(b.z + c, EPS_F) + fmaxf(b.w + c, EPS_F);
        p2 += fmaxf(cc.x + c, EPS_F) + fmaxf(cc.y + c, EPS_F)
            + fmaxf(cc.z + c, EPS_F) + fmaxf(cc.w + c, EPS_F);
        p3 += fmaxf(d.x + c, EPS_F) + fmaxf(d.y + c, EPS_F)
            + fmaxf(d.z + c, EPS_F) + fmaxf(d.w + c, EPS_F);
    }
    for (; i < n4; i += stride) {
        float4 a = l4[i];
        p0 += fmaxf(a.x + c, EPS_F) + fmaxf(a.y + c, EPS_F)
            + fmaxf(a.z + c, EPS_F) + fmaxf(a.w + c, EPS_F);
    }
    if (blockIdx.x == 0) {
        for (int j = (n4 << 2) + (int)threadIdx.x; j < n; j += BLOCK)
            p0 += fmaxf(logits[j] + c, EPS_F);
    }

    float partial = (p0 + p1) + (p2 + p3);
    #pragma unroll
    for (int off = 32; off > 0; off >>= 1)
        partial += __shfl_down(partial, off, 64);
    __shared__ float sm[BLOCK / 64];
    const int lane = threadIdx.x & 63;
    const int wv   = threadIdx.x >> 6;
    if (lane == 0) sm[wv] = partial;
    __syncthreads();
    if (threadIdx.x == 0) {
        float bsum = sm[0];
        #pragma unroll
        for (int w = 1; w < BLOCK / 64; ++w) bsum += sm[w];
        partials[blockIdx.x] = bsum;          // non-atomic, always written
    }
}

__global__ __launch_bounds__(BLOCK) void finalize_kernel(
        const float* __restrict__ partials,
        float* __restrict__ out, int n) {
    double s = 0.0;
    for (int j = threadIdx.x; j < GRID; j += BLOCK)
        s += (double)partials[j];
    #pragma unroll
    for (int off = 32; off > 0; off >>= 1)
        s += __shfl_down(s, off, 64);
    __shared__ double sm[BLOCK / 64];
    const int lane = threadIdx.x & 63;
    const int wv   = threadIdx.x >> 6;
    if (lane == 0) sm[wv] = s;
    __syncthreads();
    if (threadIdx.x == 0) {
        double t = sm[0];
        #pragma unroll
        for (int w = 1; w < BLOCK / 64; ++w) t += sm[w];
        out[0] = (float)(t / (double)n);
    }
}

extern "C" void kernel_launch(void* const* d_in, const int* in_sizes, int n_in,
                              void* d_out, int out_size, void* d_ws, size_t ws_size,
                              hipStream_t stream) {
    const float* logits = (const float*)d_in[0];
    const int*   labels = (const int*)d_in[1];
    const int n_logits = in_sizes[0];
    const int n_labels = in_sizes[1];

    float* partials = (float*)d_ws;
    int*   idx      = (int*)((char*)d_ws + GRID * sizeof(float));

    find_label_kernel<<<GRID, BLOCK, 0, stream>>>(labels, n_labels, idx);
    clamped_sum_kernel<<<GRID, BLOCK, 0, stream>>>(logits, n_logits, idx, partials);
    finalize_kernel<<<1, BLOCK, 0, stream>>>(partials, (float*)d_out, n_logits);
}